// Round 4
// baseline (1810.459 us; speedup 1.0000x reference)
//
#include <hip/hip_runtime.h>
#include <hip/hip_bf16.h>
#include <math.h>

#define BATCH 2
#define SEQ   2048
#define DMODEL 512
#define NHEAD 8
#define DEPTH 64   // DMODEL / NHEAD

// ---------------- Threefry-2x32, JAX partitionable mode ----------------
// Element flat index f gets counter pair (hi,lo) = (f>>32, f&0xffffffff) = (0, f)
// for f < 2^32; output bits = y0 ^ y1 (JAX _threefry_random_bits_partitionable).
__device__ __forceinline__ unsigned tf_bits_part(unsigned k0, unsigned k1,
                                                 unsigned c_hi, unsigned c_lo) {
    unsigned x0 = c_hi, x1 = c_lo;
    unsigned ks2 = 0x1BD11BDAu ^ k0 ^ k1;
    x0 += k0; x1 += k1;
#define TF_RND(r) { x0 += x1; x1 = (x1 << r) | (x1 >> (32 - r)); x1 ^= x0; }
    TF_RND(13) TF_RND(15) TF_RND(26) TF_RND(6)
    x0 += k1;  x1 += ks2 + 1u;
    TF_RND(17) TF_RND(29) TF_RND(16) TF_RND(24)
    x0 += ks2; x1 += k0 + 2u;
    TF_RND(13) TF_RND(15) TF_RND(26) TF_RND(6)
    x0 += k0;  x1 += k1 + 3u;
    TF_RND(17) TF_RND(29) TF_RND(16) TF_RND(24)
    x0 += k1;  x1 += ks2 + 4u;
    TF_RND(13) TF_RND(15) TF_RND(26) TF_RND(6)
    x0 += ks2; x1 += k0 + 5u;
#undef TF_RND
    return x0 ^ x1;
}

__device__ __forceinline__ float tf_uniform(unsigned k0, unsigned k1, unsigned f) {
    unsigned bits = tf_bits_part(k0, k1, 0u, f);
    return __uint_as_float((bits >> 9) | 0x3f800000u) - 1.0f;
}

// ---------------- fp32 GEMM: C[M,N] = A[M,K] @ W[K,N] (+bias) ----------------
__global__ __launch_bounds__(256) void gemm_f32(
        const float* __restrict__ A, const float* __restrict__ Wm,
        const float* __restrict__ bias, float* __restrict__ C,
        int M, int N, int K) {
    __shared__ float As[32][33];
    __shared__ float Bs[32][33];
    const int tcol = threadIdx.x & 31;   // 0..31
    const int trow = threadIdx.x >> 5;   // 0..7
    const int row0 = blockIdx.y * 32;
    const int col0 = blockIdx.x * 32;
    float acc[4] = {0.f, 0.f, 0.f, 0.f};
    for (int kk0 = 0; kk0 < K; kk0 += 32) {
#pragma unroll
        for (int i = 0; i < 4; ++i) {
            int r = trow + i * 8;
            As[r][tcol] = A[(size_t)(row0 + r) * K + kk0 + tcol];
            Bs[r][tcol] = Wm[(size_t)(kk0 + r) * N + col0 + tcol];
        }
        __syncthreads();
#pragma unroll
        for (int kk = 0; kk < 32; ++kk) {
            float bv = Bs[kk][tcol];
#pragma unroll
            for (int i = 0; i < 4; ++i)
                acc[i] += As[trow + i * 8][kk] * bv;
        }
        __syncthreads();
    }
#pragma unroll
    for (int i = 0; i < 4; ++i) {
        int r = row0 + trow + i * 8;
        float vout = acc[i] + (bias ? bias[col0 + tcol] : 0.0f);
        C[(size_t)r * N + col0 + tcol] = vout;
    }
}

// ---------------- inverse L2 norm per (b,s,h) ----------------
__global__ __launch_bounds__(256) void rnorm_kernel(const float* __restrict__ q,
                                                    float* __restrict__ rn) {
    int idx = blockIdx.x * blockDim.x + threadIdx.x;  // (b*S+s)*H + h
    if (idx >= BATCH * SEQ * NHEAD) return;
    int h = idx & (NHEAD - 1);
    int bs = idx >> 3;
    const float* p = q + (size_t)bs * DMODEL + h * DEPTH;
    float s = 0.f;
#pragma unroll
    for (int j = 0; j < DEPTH; ++j) { float x = p[j]; s += x * x; }
    rn[idx] = 1.0f / sqrtf(s);
}

// ---------------- attention: one wave (64 lanes) per (b,h,qrow) ----------------
__global__ __launch_bounds__(64) void attn_kernel(
        const float* __restrict__ q,   // [B,S,D]
        const float* __restrict__ vv,  // [B,S,D]
        const float* __restrict__ rn,  // [B,S,H]
        const int* __restrict__ seedp,
        float* __restrict__ out) {     // [B,S,D]
    const int bid  = blockIdx.x;          // b*(H*S) + h*S + qrow
    const int qrow = bid & (SEQ - 1);
    const int bh   = bid >> 11;
    const int h    = bh & (NHEAD - 1);
    const int b    = bh >> 3;
    const int lane = threadIdx.x;         // 0..63

    const unsigned k0 = 0u;
    const unsigned k1 = (unsigned)seedp[0];

    __shared__ float qs[DEPTH];
    __shared__ float p[SEQ];

    const float* qhead = q  + (size_t)b * SEQ * DMODEL + h * DEPTH;
    const float* vhead = vv + (size_t)b * SEQ * DMODEL + h * DEPTH;
    qs[lane] = qhead[(size_t)qrow * DMODEL + lane];
    __syncthreads();

    // flat dropout index: f = b*2^25 + h*2^22 + qrow*2^11 + k
    const unsigned fbase = ((unsigned)b << 25) | ((unsigned)h << 22) | ((unsigned)qrow << 11);
    float acc = 0.0f;

    if (qrow == 0) {
        // only the self entry survives: attn[0,0] = 1.0
        float u = tf_uniform(k0, k1, fbase);
        float w = (u < 0.9f) ? (1.0f / 0.9f) : 0.0f;
        acc = w * vhead[lane];
    } else {
        // logits for k in [0, qrow)  (diagonal underflows to 0, future masked)
        float lmax = -1e30f;
        for (int k = lane; k < qrow; k += 64) {
            const float* qk = qhead + (size_t)k * DMODEL;
            float dot = 0.f;
#pragma unroll
            for (int j = 0; j < DEPTH; ++j) dot += qs[j] * qk[j];
            float lg = dot * rn[((size_t)b * SEQ + k) * NHEAD + h] * 0.125f;
            p[k] = lg;
            lmax = fmaxf(lmax, lg);
        }
#pragma unroll
        for (int off = 32; off; off >>= 1) lmax = fmaxf(lmax, __shfl_xor(lmax, off));
        float lsum = 0.f;
        for (int k = lane; k < qrow; k += 64) {
            float e = expf(p[k] - lmax);
            p[k] = e;
            lsum += e;
        }
#pragma unroll
        for (int off = 32; off; off >>= 1) lsum += __shfl_xor(lsum, off);
        const float inv = 1.0f / lsum;
        // normalize + dropout
        for (int k = lane; k < qrow; k += 64) {
            float u = tf_uniform(k0, k1, fbase + (unsigned)k);
            p[k] = (u < 0.9f) ? (p[k] * inv) / 0.9f : 0.0f;
        }
        __syncthreads();
        // PV: lane owns depth index d = lane
        for (int k = 0; k < qrow; ++k)
            acc += p[k] * vhead[(size_t)k * DMODEL + lane];
    }
    out[((size_t)b * SEQ + qrow) * DMODEL + h * DEPTH + lane] = acc;
}

// ---------------- launcher ----------------
extern "C" void kernel_launch(void* const* d_in, const int* in_sizes, int n_in,
                              void* d_out, int out_size, void* d_ws, size_t ws_size,
                              hipStream_t stream) {
    const float* qk    = (const float*)d_in[0];
    const float* v     = (const float*)d_in[1];
    const float* W_qk  = (const float*)d_in[2];
    const float* W_v   = (const float*)d_in[3];
    const float* W_out = (const float*)d_in[4];
    const float* b_out = (const float*)d_in[5];
    const int*   seedp = (const int*)d_in[6];
    float* out = (float*)d_out;

    const size_t NELT = (size_t)BATCH * SEQ * DMODEL;  // 2,097,152
    float* q_buf  = (float*)d_ws;
    float* vv_buf = q_buf + NELT;
    float* ao_buf = vv_buf + NELT;
    float* rn_buf = ao_buf + NELT;

    const int M = BATCH * SEQ;

    dim3 gb(256);
    dim3 gg(DMODEL / 32, M / 32);
    hipLaunchKernelGGL(gemm_f32, gg, gb, 0, stream, qk, W_qk, nullptr, q_buf, M, DMODEL, DMODEL);
    hipLaunchKernelGGL(gemm_f32, gg, gb, 0, stream, v, W_v, nullptr, vv_buf, M, DMODEL, DMODEL);

    hipLaunchKernelGGL(rnorm_kernel, dim3((BATCH * SEQ * NHEAD + 255) / 256), dim3(256), 0, stream,
                       q_buf, rn_buf);

    hipLaunchKernelGGL(attn_kernel, dim3(BATCH * NHEAD * SEQ), dim3(64), 0, stream,
                       q_buf, vv_buf, rn_buf, seedp, ao_buf);

    hipLaunchKernelGGL(gemm_f32, gg, gb, 0, stream, ao_buf, W_out, b_out, out, M, DMODEL, DMODEL);
}

// Round 5
// 1151.363 us; speedup vs baseline: 1.5724x; 1.5724x over previous
//
#include <hip/hip_runtime.h>
#include <hip/hip_bf16.h>
#include <math.h>

#define BATCH 2
#define SEQ   2048
#define DMODEL 512
#define NHEAD 8
#define DEPTH 64   // DMODEL / NHEAD

// ---------------- Threefry-2x32, JAX partitionable mode (verified R4) ----------------
__device__ __forceinline__ unsigned tf_bits_part(unsigned k0, unsigned k1,
                                                 unsigned c_hi, unsigned c_lo) {
    unsigned x0 = c_hi, x1 = c_lo;
    unsigned ks2 = 0x1BD11BDAu ^ k0 ^ k1;
    x0 += k0; x1 += k1;
#define TF_RND(r) { x0 += x1; x1 = (x1 << r) | (x1 >> (32 - r)); x1 ^= x0; }
    TF_RND(13) TF_RND(15) TF_RND(26) TF_RND(6)
    x0 += k1;  x1 += ks2 + 1u;
    TF_RND(17) TF_RND(29) TF_RND(16) TF_RND(24)
    x0 += ks2; x1 += k0 + 2u;
    TF_RND(13) TF_RND(15) TF_RND(26) TF_RND(6)
    x0 += k0;  x1 += k1 + 3u;
    TF_RND(17) TF_RND(29) TF_RND(16) TF_RND(24)
    x0 += k1;  x1 += ks2 + 4u;
    TF_RND(13) TF_RND(15) TF_RND(26) TF_RND(6)
    x0 += ks2; x1 += k0 + 5u;
#undef TF_RND
    return x0 ^ x1;
}

__device__ __forceinline__ float tf_uniform(unsigned k1, unsigned f) {
    unsigned bits = tf_bits_part(0u, k1, 0u, f);
    return __uint_as_float((bits >> 9) | 0x3f800000u) - 1.0f;
}

// ---------------- fp32 GEMM: C[M,N] = A[M,K] @ W[K,N] (+bias) ----------------
__global__ __launch_bounds__(256) void gemm_f32(
        const float* __restrict__ A, const float* __restrict__ Wm,
        const float* __restrict__ bias, float* __restrict__ C,
        int M, int N, int K) {
    __shared__ float As[32][33];
    __shared__ float Bs[32][33];
    const int tcol = threadIdx.x & 31;
    const int trow = threadIdx.x >> 5;
    const int row0 = blockIdx.y * 32;
    const int col0 = blockIdx.x * 32;
    float acc[4] = {0.f, 0.f, 0.f, 0.f};
    for (int kk0 = 0; kk0 < K; kk0 += 32) {
#pragma unroll
        for (int i = 0; i < 4; ++i) {
            int r = trow + i * 8;
            As[r][tcol] = A[(size_t)(row0 + r) * K + kk0 + tcol];
            Bs[r][tcol] = Wm[(size_t)(kk0 + r) * N + col0 + tcol];
        }
        __syncthreads();
#pragma unroll
        for (int kk = 0; kk < 32; ++kk) {
            float bv = Bs[kk][tcol];
#pragma unroll
            for (int i = 0; i < 4; ++i)
                acc[i] += As[trow + i * 8][kk] * bv;
        }
        __syncthreads();
    }
#pragma unroll
    for (int i = 0; i < 4; ++i) {
        int r = row0 + trow + i * 8;
        float vout = acc[i] + (bias ? bias[col0 + tcol] : 0.0f);
        C[(size_t)r * N + col0 + tcol] = vout;
    }
}

// ---------------- qn = per-(b,s,h) L2-normalized q ----------------
__global__ __launch_bounds__(256) void qnorm_kernel(const float* __restrict__ q,
                                                    float* __restrict__ qn) {
    const int u    = blockIdx.x * 4 + (threadIdx.x >> 6);  // (b*S+s)*H + h
    const int lane = threadIdx.x & 63;
    const int h  = u & (NHEAD - 1);
    const int bs = u >> 3;
    const size_t idx = (size_t)bs * DMODEL + h * DEPTH + lane;
    float x = q[idx];
    float ss = x * x;
#pragma unroll
    for (int off = 32; off; off >>= 1) ss += __shfl_xor(ss, off);
    qn[idx] = x * rsqrtf(ss);
}

// ---------------- flash attention (fp32), 64 q-rows/block, K-tile 64 ----------------
// LDS: QsT[j][r] (Q^T, x0.125) [64][68]; KV shared buffer (K stride 66 / V stride 68);
// pL per-wave dropped-P [16][64].  3 blocks/CU.
__global__ __launch_bounds__(256, 3) void attn_flash(
        const float* __restrict__ q,   // [B,S,D] projected
        const float* __restrict__ qn,  // [B,S,D] normalized key copy
        const float* __restrict__ vv,  // [B,S,D] projected V
        const int* __restrict__ seedp,
        float* __restrict__ out) {     // [B,S,D]
    __shared__ __align__(16) float QsT[64 * 68];
    __shared__ __align__(16) float KV[64 * 68];
    __shared__ __align__(16) float pL[4][16 * 64];

    const unsigned u = blockIdx.x;
    const int bh = u >> 5;             // 0..15
    const int b  = bh >> 3;
    const int h  = bh & (NHEAD - 1);
    const int i5 = u & 31;
    const int qb = ((u >> 8) & 1) ? (31 - i5) : i5;  // workload-balanced pairing
    const int w    = threadIdx.x >> 6;  // wave 0..3
    const int lane = threadIdx.x & 63;
    const int tid  = threadIdx.x;
    const unsigned seed = (unsigned)seedp[0];

    const int r0 = qb * 64;
    const size_t headoff = (size_t)b * SEQ * DMODEL + h * DEPTH;
    const float* qh  = q  + headoff;
    const float* qnh = qn + headoff;
    const float* vh  = vv + headoff;

    // stage Q^T once, folded 1/sqrt(depth)=0.125
    for (int i = 0; i < 16; ++i) {
        int e = tid + i * 256;
        int r = e >> 6, j = e & 63;
        QsT[j * 68 + r] = qh[(size_t)(r0 + r) * DMODEL + j] * 0.125f;
    }

    float m[16], l[16], acc[16];
#pragma unroll
    for (int r = 0; r < 16; ++r) { m[r] = -1e20f; l[r] = 0.f; acc[r] = 0.f; }

    const int rbase = r0 + w * 16;
    const unsigned fb0 = ((unsigned)b << 25) | ((unsigned)h << 22);
    float* pW = pL[w];

    for (int kt = 0; kt <= qb; ++kt) {
        const int k0 = kt * 64;
        __syncthreads();   // protect KV reuse (prev PV) + QsT on first iter
        // stage K tile (normalized), row-major stride 66
        for (int i = 0; i < 16; ++i) {
            int e = tid + i * 256;
            int kr = e >> 6, j = e & 63;
            KV[kr * 66 + j] = qnh[(size_t)(k0 + kr) * DMODEL + j];
        }
        __syncthreads();

        // QK^T: lane owns column k = k0+lane; wave owns rows rbase..rbase+15
        float s[16];
#pragma unroll
        for (int r = 0; r < 16; ++r) s[r] = 0.f;
#pragma unroll 4
        for (int j = 0; j < 64; ++j) {
            float kv = KV[lane * 66 + j];
            const float4* qv = (const float4*)&QsT[j * 68 + w * 16];
            float4 q0 = qv[0], q1 = qv[1], q2 = qv[2], q3 = qv[3];
            s[0]  += q0.x * kv; s[1]  += q0.y * kv; s[2]  += q0.z * kv; s[3]  += q0.w * kv;
            s[4]  += q1.x * kv; s[5]  += q1.y * kv; s[6]  += q1.z * kv; s[7]  += q1.w * kv;
            s[8]  += q2.x * kv; s[9]  += q2.y * kv; s[10] += q2.z * kv; s[11] += q2.w * kv;
            s[12] += q3.x * kv; s[13] += q3.y * kv; s[14] += q3.z * kv; s[15] += q3.w * kv;
        }

        // online softmax + dropout; write dropped P to per-wave LDS
#pragma unroll
        for (int r = 0; r < 16; ++r) {
            const int rw = rbase + r;
            float sv = (k0 + lane >= rw) ? -1e30f : s[r];  // strict causal (+self)
            float mx = sv;
#pragma unroll
            for (int off = 32; off; off >>= 1) mx = fmaxf(mx, __shfl_xor(mx, off));
            float mnew  = fmaxf(m[r], mx);
            float alpha = __expf(m[r] - mnew);
            float p     = __expf(sv - mnew);
            float rs = p;
#pragma unroll
            for (int off = 32; off; off >>= 1) rs += __shfl_xor(rs, off);
            l[r]   = l[r] * alpha + rs;
            acc[r] *= alpha;
            m[r]   = mnew;
            unsigned f = (fb0 | ((unsigned)rw << 11)) + (unsigned)(k0 + lane);
            float uu = tf_uniform(seed, f);
            pW[r * 64 + lane] = (uu < 0.9f) ? p * (1.0f / 0.9f) : 0.0f;
        }

        __syncthreads();   // all waves done with K before overwrite; orders pL too
        // stage V tile, row-major stride 68
        for (int i = 0; i < 16; ++i) {
            int e = tid + i * 256;
            int kr = e >> 6, d = e & 63;
            KV[kr * 68 + d] = vh[(size_t)(k0 + kr) * DMODEL + d];
        }
        __syncthreads();

        // PV: lane owns d = lane
        for (int kq = 0; kq < 16; ++kq) {
            float v0 = KV[(4 * kq + 0) * 68 + lane];
            float v1 = KV[(4 * kq + 1) * 68 + lane];
            float v2 = KV[(4 * kq + 2) * 68 + lane];
            float v3 = KV[(4 * kq + 3) * 68 + lane];
#pragma unroll
            for (int r = 0; r < 16; ++r) {
                const float4 pq = *(const float4*)&pW[r * 64 + 4 * kq];
                acc[r] += pq.x * v0 + pq.y * v1 + pq.z * v2 + pq.w * v3;
            }
        }
    }

    // epilogue: normalize by l; row 0 = dropout(1)*vv[0]
#pragma unroll
    for (int r = 0; r < 16; ++r) {
        const int rw = rbase + r;
        float o;
        if (rw == 0) {
            float uu = tf_uniform(seed, fb0);
            o = ((uu < 0.9f) ? (1.0f / 0.9f) : 0.0f) * vh[lane];
        } else {
            o = acc[r] / l[r];
        }
        out[headoff + (size_t)rw * DMODEL + lane] = o;
    }
}

// ---------------- launcher ----------------
extern "C" void kernel_launch(void* const* d_in, const int* in_sizes, int n_in,
                              void* d_out, int out_size, void* d_ws, size_t ws_size,
                              hipStream_t stream) {
    const float* qk    = (const float*)d_in[0];
    const float* v     = (const float*)d_in[1];
    const float* W_qk  = (const float*)d_in[2];
    const float* W_v   = (const float*)d_in[3];
    const float* W_out = (const float*)d_in[4];
    const float* b_out = (const float*)d_in[5];
    const int*   seedp = (const int*)d_in[6];
    float* out = (float*)d_out;

    const size_t NELT = (size_t)BATCH * SEQ * DMODEL;  // 2,097,152
    float* q_buf  = (float*)d_ws;
    float* vv_buf = q_buf + NELT;
    float* ao_buf = vv_buf + NELT;
    float* qn_buf = ao_buf + NELT;

    const int M = BATCH * SEQ;

    dim3 gb(256);
    dim3 gg(DMODEL / 32, M / 32);
    hipLaunchKernelGGL(gemm_f32, gg, gb, 0, stream, qk, W_qk, nullptr, q_buf, M, DMODEL, DMODEL);
    hipLaunchKernelGGL(gemm_f32, gg, gb, 0, stream, v, W_v, nullptr, vv_buf, M, DMODEL, DMODEL);

    hipLaunchKernelGGL(qnorm_kernel, dim3(BATCH * SEQ * NHEAD / 4), dim3(256), 0, stream,
                       q_buf, qn_buf);

    hipLaunchKernelGGL(attn_flash, dim3(BATCH * NHEAD * (SEQ / 64)), dim3(256), 0, stream,
                       q_buf, qn_buf, vv_buf, seedp, ao_buf);

    hipLaunchKernelGGL(gemm_f32, gg, gb, 0, stream, ao_buf, W_out, b_out, out, M, DMODEL, DMODEL);
}

// Round 9
// 572.792 us; speedup vs baseline: 3.1608x; 2.0101x over previous
//
#include <hip/hip_runtime.h>
#include <hip/hip_bf16.h>
#include <math.h>

#define BATCH 2
#define SEQ   2048
#define DMODEL 512
#define NHEAD 8
#define DEPTH 64   // DMODEL / NHEAD

// ---------------- Threefry-2x32, JAX partitionable mode (verified R4) ----------------
__device__ __forceinline__ unsigned tf_bits_part(unsigned k0, unsigned k1,
                                                 unsigned c_hi, unsigned c_lo) {
    unsigned x0 = c_hi, x1 = c_lo;
    unsigned ks2 = 0x1BD11BDAu ^ k0 ^ k1;
    x0 += k0; x1 += k1;
#define TF_RND(r) { x0 += x1; x1 = (x1 << r) | (x1 >> (32 - r)); x1 ^= x0; }
    TF_RND(13) TF_RND(15) TF_RND(26) TF_RND(6)
    x0 += k1;  x1 += ks2 + 1u;
    TF_RND(17) TF_RND(29) TF_RND(16) TF_RND(24)
    x0 += ks2; x1 += k0 + 2u;
    TF_RND(13) TF_RND(15) TF_RND(26) TF_RND(6)
    x0 += k0;  x1 += k1 + 3u;
    TF_RND(17) TF_RND(29) TF_RND(16) TF_RND(24)
    x0 += k1;  x1 += ks2 + 4u;
    TF_RND(13) TF_RND(15) TF_RND(26) TF_RND(6)
    x0 += ks2; x1 += k0 + 5u;
#undef TF_RND
    return x0 ^ x1;
}

__device__ __forceinline__ float tf_uniform(unsigned k1, unsigned f) {
    unsigned bits = tf_bits_part(0u, k1, 0u, f);
    return __uint_as_float((bits >> 9) | 0x3f800000u) - 1.0f;
}

// ---------------- fp32 GEMM 64x64 tile: C[M,N] = A[M,K] @ W[K,N] (+bias) ----------------
__global__ __launch_bounds__(256) void gemm64(
        const float* __restrict__ A, const float* __restrict__ Wm,
        const float* __restrict__ bias, float* __restrict__ C,
        int M, int N, int K) {
    __shared__ __align__(16) float As[64][36];   // [row][k] pad->36 (16B-aligned rows)
    __shared__ __align__(16) float Bs[32][68];   // [k][col]
    const int tid = threadIdx.x;
    const int tx = tid & 15;        // col group 0..15
    const int ty = tid >> 4;        // row group 0..15
    const int row0 = blockIdx.y * 64;
    const int col0 = blockIdx.x * 64;

    float acc[4][4];
#pragma unroll
    for (int i = 0; i < 4; ++i)
#pragma unroll
        for (int j = 0; j < 4; ++j) acc[i][j] = 0.f;

    for (int k0 = 0; k0 < K; k0 += 32) {
        // stage A tile: 64 rows x 32 k = 512 float4, 2 per thread
#pragma unroll
        for (int i = 0; i < 2; ++i) {
            int e = tid + i * 256;
            int r = e >> 3, c4 = (e & 7) * 4;
            float4 fa = *(const float4*)&A[(size_t)(row0 + r) * K + k0 + c4];
            *(float4*)&As[r][c4] = fa;
        }
        // stage B tile: 32 k x 64 cols = 512 float4, 2 per thread
#pragma unroll
        for (int i = 0; i < 2; ++i) {
            int e = tid + i * 256;
            int kr = e >> 4, c4 = (e & 15) * 4;
            float4 fb = *(const float4*)&Wm[(size_t)(k0 + kr) * N + col0 + c4];
            *(float4*)&Bs[kr][c4] = fb;
        }
        __syncthreads();
#pragma unroll 4
        for (int kk = 0; kk < 32; ++kk) {
            float4 b4 = *(const float4*)&Bs[kk][tx * 4];
            float a0 = As[ty * 4 + 0][kk];
            float a1 = As[ty * 4 + 1][kk];
            float a2 = As[ty * 4 + 2][kk];
            float a3 = As[ty * 4 + 3][kk];
            acc[0][0] += a0 * b4.x; acc[0][1] += a0 * b4.y; acc[0][2] += a0 * b4.z; acc[0][3] += a0 * b4.w;
            acc[1][0] += a1 * b4.x; acc[1][1] += a1 * b4.y; acc[1][2] += a1 * b4.z; acc[1][3] += a1 * b4.w;
            acc[2][0] += a2 * b4.x; acc[2][1] += a2 * b4.y; acc[2][2] += a2 * b4.z; acc[2][3] += a2 * b4.w;
            acc[3][0] += a3 * b4.x; acc[3][1] += a3 * b4.y; acc[3][2] += a3 * b4.z; acc[3][3] += a3 * b4.w;
        }
        __syncthreads();
    }
    float4 bb = make_float4(0.f, 0.f, 0.f, 0.f);
    if (bias) bb = *(const float4*)&bias[col0 + tx * 4];
#pragma unroll
    for (int i = 0; i < 4; ++i) {
        float4 o = make_float4(acc[i][0] + bb.x, acc[i][1] + bb.y,
                               acc[i][2] + bb.z, acc[i][3] + bb.w);
        *(float4*)&C[(size_t)(row0 + ty * 4 + i) * N + col0 + tx * 4] = o;
    }
}

// ---------------- qn = per-(b,s,h) L2-normalized q ----------------
__global__ __launch_bounds__(256) void qnorm_kernel(const float* __restrict__ q,
                                                    float* __restrict__ qn) {
    const int u    = blockIdx.x * 4 + (threadIdx.x >> 6);  // (b*S+s)*H + h
    const int lane = threadIdx.x & 63;
    const int h  = u & (NHEAD - 1);
    const int bs = u >> 3;
    const size_t idx = (size_t)bs * DMODEL + h * DEPTH + lane;
    float x = q[idx];
    float ss = x * x;
#pragma unroll
    for (int off = 32; off; off >>= 1) ss += __shfl_xor(ss, off);
    qn[idx] = x * rsqrtf(ss);
}

// ---------------- balanced flash attention (fp32) ----------------
// Block: 512 threads (8 waves). Handles q-tiles {63-p, p} of one (b,h): exactly 33
// k-tile units each block. Wave w owns 4 q-rows of the active 32-row tile.
// LDS 34816 B; grid 512 -> 2 blocks/CU -> 16 waves/CU, perfectly balanced.
__global__ __launch_bounds__(512, 2) void attn_flash(
        const float* __restrict__ q,   // [B,S,D] projected
        const float* __restrict__ qn,  // [B,S,D] normalized key copy
        const float* __restrict__ vv,  // [B,S,D] projected V
        const int* __restrict__ seedp,
        float* __restrict__ out) {     // [B,S,D]
    __shared__ __align__(16) float QsT[64 * 36];      // Q^T [j][r] x0.125, 32 rows used
    __shared__ __align__(16) float KV[64 * 68];       // K stride 66 / V stride 68
    __shared__ __align__(16) float pL[8][4 * 64];     // per-wave dropped P

    const unsigned n = blockIdx.x;
    const int xcd  = n & 7;
    const int bh   = xcd * 2 + ((n >> 3) & 1);  // XCD gets 2 heads -> K/V fits its L2
    const int pair = n >> 4;                    // 0..31
    const int b = bh >> 3;
    const int h = bh & (NHEAD - 1);
    const int w    = threadIdx.x >> 6;
    const int lane = threadIdx.x & 63;
    const int tid  = threadIdx.x;
    const unsigned seed = (unsigned)seedp[0];

    const size_t headoff = (size_t)b * SEQ * DMODEL + h * DEPTH;
    const float* qh  = q  + headoff;
    const float* qnh = qn + headoff;
    const float* vh  = vv + headoff;
    const unsigned fb0 = ((unsigned)b << 25) | ((unsigned)h << 22);

    for (int ti = 0; ti < 2; ++ti) {
        const int t  = ti ? pair : (63 - pair);  // big tile first
        const int r0 = t * 32;
        const int nk = t / 2 + 1;

        // stage Q^T (32 rows x 64 j), folded 0.125
#pragma unroll
        for (int i = 0; i < 4; ++i) {
            int e = tid + i * 512;
            int r = e >> 6, j = e & 63;
            QsT[j * 36 + r] = qh[(size_t)(r0 + r) * DMODEL + j] * 0.125f;
        }

        float m[4], l[4], acc[4];
#pragma unroll
        for (int r = 0; r < 4; ++r) { m[r] = -1e20f; l[r] = 0.f; acc[r] = 0.f; }
        const int rbase = r0 + w * 4;
        float* pW = pL[w];

        for (int kt = 0; kt < nk; ++kt) {
            const int k0 = kt * 64;
            __syncthreads();   // KV reusable (prev PV done) + QsT staged
            // stage K tile (normalized), stride 66
#pragma unroll
            for (int i = 0; i < 8; ++i) {
                int e = tid + i * 512;
                int kr = e >> 6, j = e & 63;
                KV[kr * 66 + j] = qnh[(size_t)(k0 + kr) * DMODEL + j];
            }
            __syncthreads();

            // QK^T: lane owns column k0+lane; wave owns rows rbase..rbase+3
            float s0 = 0.f, s1 = 0.f, s2 = 0.f, s3 = 0.f;
#pragma unroll 8
            for (int j = 0; j < 64; ++j) {
                float kv = KV[lane * 66 + j];
                float4 qv = *(const float4*)&QsT[j * 36 + w * 4];
                s0 += qv.x * kv; s1 += qv.y * kv; s2 += qv.z * kv; s3 += qv.w * kv;
            }
            float sr[4] = {s0, s1, s2, s3};

            // online softmax + dropout -> pW
#pragma unroll
            for (int r = 0; r < 4; ++r) {
                const int rw = rbase + r;
                float sv = (k0 + lane >= rw) ? -1e30f : sr[r];  // strict causal (+self)
                float mx = sv;
#pragma unroll
                for (int off = 32; off; off >>= 1) mx = fmaxf(mx, __shfl_xor(mx, off));
                float mnew  = fmaxf(m[r], mx);
                float alpha = __expf(m[r] - mnew);
                float p     = __expf(sv - mnew);
                float rs = p;
#pragma unroll
                for (int off = 32; off; off >>= 1) rs += __shfl_xor(rs, off);
                l[r]   = l[r] * alpha + rs;
                acc[r] *= alpha;
                m[r]   = mnew;
                unsigned f = (fb0 | ((unsigned)rw << 11)) + (unsigned)(k0 + lane);
                float uu = tf_uniform(seed, f);
                pW[r * 64 + lane] = (uu < 0.9f) ? p * (1.0f / 0.9f) : 0.0f;
            }

            __syncthreads();   // all waves done reading K
            // stage V tile, stride 68
#pragma unroll
            for (int i = 0; i < 8; ++i) {
                int e = tid + i * 512;
                int kr = e >> 6, d = e & 63;
                KV[kr * 68 + d] = vh[(size_t)(k0 + kr) * DMODEL + d];
            }
            __syncthreads();

            // PV: lane owns d = lane
#pragma unroll 4
            for (int kq = 0; kq < 16; ++kq) {
                float v0 = KV[(4 * kq + 0) * 68 + lane];
                float v1 = KV[(4 * kq + 1) * 68 + lane];
                float v2 = KV[(4 * kq + 2) * 68 + lane];
                float v3 = KV[(4 * kq + 3) * 68 + lane];
#pragma unroll
                for (int r = 0; r < 4; ++r) {
                    const float4 pq = *(const float4*)&pW[r * 64 + 4 * kq];
                    acc[r] += pq.x * v0 + pq.y * v1 + pq.z * v2 + pq.w * v3;
                }
            }
        }

        // epilogue for this tile
#pragma unroll
        for (int r = 0; r < 4; ++r) {
            const int rw = rbase + r;
            float o;
            if (rw == 0) {
                float uu = tf_uniform(seed, fb0);
                o = ((uu < 0.9f) ? (1.0f / 0.9f) : 0.0f) * vh[lane];
            } else {
                o = acc[r] / l[r];
            }
            out[headoff + (size_t)rw * DMODEL + lane] = o;
        }
        __syncthreads();   // QsT/KV safe to restage for second tile
    }
}

// ---------------- launcher ----------------
extern "C" void kernel_launch(void* const* d_in, const int* in_sizes, int n_in,
                              void* d_out, int out_size, void* d_ws, size_t ws_size,
                              hipStream_t stream) {
    const float* qk    = (const float*)d_in[0];
    const float* v     = (const float*)d_in[1];
    const float* W_qk  = (const float*)d_in[2];
    const float* W_v   = (const float*)d_in[3];
    const float* W_out = (const float*)d_in[4];
    const float* b_out = (const float*)d_in[5];
    const int*   seedp = (const int*)d_in[6];
    float* out = (float*)d_out;

    const size_t NELT = (size_t)BATCH * SEQ * DMODEL;  // 2,097,152
    float* q_buf  = (float*)d_ws;
    float* vv_buf = q_buf + NELT;
    float* ao_buf = vv_buf + NELT;
    float* qn_buf = ao_buf + NELT;

    const int M = BATCH * SEQ;

    dim3 gb(256);
    dim3 gg(DMODEL / 64, M / 64);
    hipLaunchKernelGGL(gemm64, gg, gb, 0, stream, qk, W_qk, nullptr, q_buf, M, DMODEL, DMODEL);
    hipLaunchKernelGGL(gemm64, gg, gb, 0, stream, v, W_v, nullptr, vv_buf, M, DMODEL, DMODEL);

    hipLaunchKernelGGL(qnorm_kernel, dim3(BATCH * SEQ * NHEAD / 4), dim3(256), 0, stream,
                       q_buf, qn_buf);

    hipLaunchKernelGGL(attn_flash, dim3(512), dim3(512), 0, stream,
                       q_buf, qn_buf, vv_buf, seedp, ao_buf);

    hipLaunchKernelGGL(gemm64, gg, gb, 0, stream, ao_buf, W_out, b_out, out, M, DMODEL, DMODEL);
}

// Round 13
// 401.690 us; speedup vs baseline: 4.5071x; 1.4260x over previous
//
#include <hip/hip_runtime.h>
#include <hip/hip_bf16.h>
#include <math.h>

#define BATCH 2
#define SEQ   2048
#define DMODEL 512
#define NHEAD 8
#define DEPTH 64   // DMODEL / NHEAD

typedef _Float16 f16x8 __attribute__((ext_vector_type(8)));
typedef float    f32x4 __attribute__((ext_vector_type(4)));
typedef unsigned u32x4 __attribute__((ext_vector_type(4)));

// ---------------- Threefry-2x32, JAX partitionable mode (verified R4/R9) ----------------
__device__ __forceinline__ unsigned tf_bits_part(unsigned k0, unsigned k1,
                                                 unsigned c_hi, unsigned c_lo) {
    unsigned x0 = c_hi, x1 = c_lo;
    unsigned ks2 = 0x1BD11BDAu ^ k0 ^ k1;
    x0 += k0; x1 += k1;
#define TF_RND(r) { x0 += x1; x1 = (x1 << r) | (x1 >> (32 - r)); x1 ^= x0; }
    TF_RND(13) TF_RND(15) TF_RND(26) TF_RND(6)
    x0 += k1;  x1 += ks2 + 1u;
    TF_RND(17) TF_RND(29) TF_RND(16) TF_RND(24)
    x0 += ks2; x1 += k0 + 2u;
    TF_RND(13) TF_RND(15) TF_RND(26) TF_RND(6)
    x0 += k0;  x1 += k1 + 3u;
    TF_RND(17) TF_RND(29) TF_RND(16) TF_RND(24)
    x0 += k1;  x1 += ks2 + 4u;
    TF_RND(13) TF_RND(15) TF_RND(26) TF_RND(6)
    x0 += ks2; x1 += k0 + 5u;
#undef TF_RND
    return x0 ^ x1;
}

__device__ __forceinline__ float tf_uniform(unsigned k1, unsigned f) {
    unsigned bits = tf_bits_part(0u, k1, 0u, f);
    return __uint_as_float((bits >> 9) | 0x3f800000u) - 1.0f;
}

__device__ __forceinline__ unsigned pack2h(float lo, float hi) {
    unsigned short ul = __builtin_bit_cast(unsigned short, (_Float16)lo);
    unsigned short uh = __builtin_bit_cast(unsigned short, (_Float16)hi);
    return (unsigned)ul | ((unsigned)uh << 16);
}

// ---------------- fp32 GEMM 64x64 tile (unchanged, verified R9) ----------------
__global__ __launch_bounds__(256) void gemm64(
        const float* __restrict__ A, const float* __restrict__ Wm,
        const float* __restrict__ bias, float* __restrict__ C,
        int M, int N, int K) {
    __shared__ __align__(16) float As[64][36];
    __shared__ __align__(16) float Bs[32][68];
    const int tid = threadIdx.x;
    const int tx = tid & 15;
    const int ty = tid >> 4;
    const int row0 = blockIdx.y * 64;
    const int col0 = blockIdx.x * 64;

    float acc[4][4];
#pragma unroll
    for (int i = 0; i < 4; ++i)
#pragma unroll
        for (int j = 0; j < 4; ++j) acc[i][j] = 0.f;

    for (int k0 = 0; k0 < K; k0 += 32) {
#pragma unroll
        for (int i = 0; i < 2; ++i) {
            int e = tid + i * 256;
            int r = e >> 3, c4 = (e & 7) * 4;
            float4 fa = *(const float4*)&A[(size_t)(row0 + r) * K + k0 + c4];
            *(float4*)&As[r][c4] = fa;
        }
#pragma unroll
        for (int i = 0; i < 2; ++i) {
            int e = tid + i * 256;
            int kr = e >> 4, c4 = (e & 15) * 4;
            float4 fb = *(const float4*)&Wm[(size_t)(k0 + kr) * N + col0 + c4];
            *(float4*)&Bs[kr][c4] = fb;
        }
        __syncthreads();
#pragma unroll 4
        for (int kk = 0; kk < 32; ++kk) {
            float4 b4 = *(const float4*)&Bs[kk][tx * 4];
            float a0 = As[ty * 4 + 0][kk];
            float a1 = As[ty * 4 + 1][kk];
            float a2 = As[ty * 4 + 2][kk];
            float a3 = As[ty * 4 + 3][kk];
            acc[0][0] += a0 * b4.x; acc[0][1] += a0 * b4.y; acc[0][2] += a0 * b4.z; acc[0][3] += a0 * b4.w;
            acc[1][0] += a1 * b4.x; acc[1][1] += a1 * b4.y; acc[1][2] += a1 * b4.z; acc[1][3] += a1 * b4.w;
            acc[2][0] += a2 * b4.x; acc[2][1] += a2 * b4.y; acc[2][2] += a2 * b4.z; acc[2][3] += a2 * b4.w;
            acc[3][0] += a3 * b4.x; acc[3][1] += a3 * b4.y; acc[3][2] += a3 * b4.z; acc[3][3] += a3 * b4.w;
        }
        __syncthreads();
    }
    float4 bb = make_float4(0.f, 0.f, 0.f, 0.f);
    if (bias) bb = *(const float4*)&bias[col0 + tx * 4];
#pragma unroll
    for (int i = 0; i < 4; ++i) {
        float4 o = make_float4(acc[i][0] + bb.x, acc[i][1] + bb.y,
                               acc[i][2] + bb.z, acc[i][3] + bb.w);
        *(float4*)&C[(size_t)(row0 + ty * 4 + i) * N + col0 + tx * 4] = o;
    }
}

// ---------------- qn = per-(b,s,h) L2-normalized q (unchanged) ----------------
__global__ __launch_bounds__(256) void qnorm_kernel(const float* __restrict__ q,
                                                    float* __restrict__ qn) {
    const int u    = blockIdx.x * 4 + (threadIdx.x >> 6);
    const int lane = threadIdx.x & 63;
    const int h  = u & (NHEAD - 1);
    const int bs = u >> 3;
    const size_t idx = (size_t)bs * DMODEL + h * DEPTH + lane;
    float x = q[idx];
    float ss = x * x;
#pragma unroll
    for (int off = 32; off; off >>= 1) ss += __shfl_xor(ss, off);
    qn[idx] = x * rsqrtf(ss);
}

// ---------------- MFMA fp16 flash attention ----------------
// 512 blocks x 8 waves. Block = pair of 32-row q-tiles {63-p, p} (33 k-tiles, balanced).
// Wave wn: rh = wn>>2 (16-row half), nq = wn&3 (16-key / 16-d quarter).
// Per k-tile: 2 QK MFMA + cross-wave softmax partials in LDS + dropout + 2 PV MFMA.
// A-frag layout (CDNA, guide-checked): A[m = lane&15][k = 8*(lane>>4)+i]; B mirrored;
// C/D: col = lane&15, row = 4*(lane>>4)+reg (m89/m91).
__global__ __launch_bounds__(512, 4) void attn_mfma(
        const float* __restrict__ q,   // [B,S,D] projected
        const float* __restrict__ qn,  // [B,S,D] normalized key copy
        const float* __restrict__ vv,  // [B,S,D] projected V
        const int* __restrict__ seedp,
        float* __restrict__ out) {     // [B,S,D]
    __shared__ __align__(16) _Float16 K_lds[64 * 72];   // [key][depth] pad 72
    __shared__ __align__(16) unsigned V_lds[32 * 68];   // [k'][d] packed (2k',2k'+1) pad 68
    __shared__ __align__(16) _Float16 P_lds[32 * 72];   // [r][key] pad 72
    __shared__ __align__(16) float    ml_lds[32 * 10];  // [r][q*2 + {m,l}] pad 10

    const unsigned n = blockIdx.x;
    const int xcd  = n & 7;
    const int bh   = xcd * 2 + ((n >> 3) & 1);
    const int pair = n >> 4;                  // 0..31
    const int b = bh >> 3;
    const int h = bh & (NHEAD - 1);
    const int tid  = threadIdx.x;
    const int lane = tid & 63;
    const int wn   = tid >> 6;
    const int rh   = wn >> 2;                 // 0..1
    const int nq   = wn & 3;                  // 0..3
    const int lg   = lane >> 4;               // 0..3
    const int ll   = lane & 15;               // 0..15
    const unsigned seed = (unsigned)seedp[0];

    const size_t headoff = (size_t)b * SEQ * DMODEL + h * DEPTH;
    const float* qh  = q  + headoff;
    const float* qnh = qn + headoff;
    const float* vh  = vv + headoff;
    const unsigned fb0 = ((unsigned)b << 25) | ((unsigned)h << 22);

    for (int ti = 0; ti < 2; ++ti) {
        const int t  = ti ? pair : (63 - pair);   // big tile first
        const int r0 = t * 32;
        const int nk = t / 2 + 1;

        // Q A-fragments in registers: rows r0+rh*16+ll, depth 8*lg+i (+32*ks), x0.125
        f16x8 aq[2];
        {
            const float* qrow = qh + (size_t)(r0 + rh * 16 + ll) * DMODEL + 8 * lg;
#pragma unroll
            for (int ks = 0; ks < 2; ++ks) {
                float4 f0 = *(const float4*)(qrow + 32 * ks);
                float4 f1 = *(const float4*)(qrow + 32 * ks + 4);
                f16x8 a;
                a[0] = (_Float16)(f0.x * 0.125f); a[1] = (_Float16)(f0.y * 0.125f);
                a[2] = (_Float16)(f0.z * 0.125f); a[3] = (_Float16)(f0.w * 0.125f);
                a[4] = (_Float16)(f1.x * 0.125f); a[5] = (_Float16)(f1.y * 0.125f);
                a[6] = (_Float16)(f1.z * 0.125f); a[7] = (_Float16)(f1.w * 0.125f);
                aq[ks] = a;
            }
        }

        float m_run[4], l_run[4];
        f32x4 acc = {0.f, 0.f, 0.f, 0.f};
#pragma unroll
        for (int r = 0; r < 4; ++r) { m_run[r] = -1e20f; l_run[r] = 0.f; }

        for (int kt = 0; kt < nk; ++kt) {
            const int k0 = kt * 64;
            __syncthreads();   // prev PV done: safe to overwrite K/V

            // stage K tile: fp16 [key][depth], 8 halves per thread
            {
                int row = tid >> 3, d0 = (tid & 7) * 8;
                const float* src = qnh + (size_t)(k0 + row) * DMODEL + d0;
                float4 f0 = *(const float4*)src;
                float4 f1 = *(const float4*)(src + 4);
                f16x8 hk;
                hk[0] = (_Float16)f0.x; hk[1] = (_Float16)f0.y;
                hk[2] = (_Float16)f0.z; hk[3] = (_Float16)f0.w;
                hk[4] = (_Float16)f1.x; hk[5] = (_Float16)f1.y;
                hk[6] = (_Float16)f1.z; hk[7] = (_Float16)f1.w;
                *(f16x8*)&K_lds[row * 72 + d0] = hk;
            }
            // stage V tile packed: u32 [k'][d] = half2(V[2k'][d], V[2k'+1][d])
            {
                int kp = tid >> 4, d0 = (tid & 15) * 4;
                const float* s0 = vh + (size_t)(k0 + 2 * kp) * DMODEL + d0;
                float4 e = *(const float4*)s0;
                float4 o = *(const float4*)(s0 + DMODEL);
                u32x4 pv;
                pv.x = pack2h(e.x, o.x); pv.y = pack2h(e.y, o.y);
                pv.z = pack2h(e.z, o.z); pv.w = pack2h(e.w, o.w);
                *(u32x4*)&V_lds[kp * 68 + d0] = pv;
            }
            __syncthreads();   // K,V ready

            // QK^T: S[r][key] for wave's 16 rows x 16-key quarter
            f32x4 s = {0.f, 0.f, 0.f, 0.f};
#pragma unroll
            for (int ks = 0; ks < 2; ++ks) {
                f16x8 bk = *(const f16x8*)&K_lds[(16 * nq + ll) * 72 + 8 * lg + 32 * ks];
                s = __builtin_amdgcn_mfma_f32_16x16x32_f16(aq[ks], bk, s, 0, 0, 0);
            }

            // mask + per-wave row partials (max, sum of exp)
            const int kg = k0 + 16 * nq + ll;
            float sv[4], mq[4], ps[4];
#pragma unroll
            for (int r = 0; r < 4; ++r) {
                int rw = r0 + rh * 16 + 4 * lg + r;
                sv[r] = (kg >= rw) ? -1e30f : s[r];
                mq[r] = sv[r];
            }
#pragma unroll
            for (int off = 1; off <= 8; off <<= 1)
#pragma unroll
                for (int r = 0; r < 4; ++r) mq[r] = fmaxf(mq[r], __shfl_xor(mq[r], off));
#pragma unroll
            for (int r = 0; r < 4; ++r) ps[r] = __expf(sv[r] - mq[r]);
#pragma unroll
            for (int off = 1; off <= 8; off <<= 1)
#pragma unroll
                for (int r = 0; r < 4; ++r) ps[r] += __shfl_xor(ps[r], off);

            if (ll == 0) {
#pragma unroll
                for (int r = 0; r < 4; ++r) {
                    int rloc = rh * 16 + 4 * lg + r;
                    ml_lds[rloc * 10 + 2 * nq]     = mq[r];
                    ml_lds[rloc * 10 + 2 * nq + 1] = ps[r];
                }
            }
            __syncthreads();   // partials ready

            // combine quarters + online update (each lane for its 4 rows)
#pragma unroll
            for (int r = 0; r < 4; ++r) {
                int rloc = rh * 16 + 4 * lg + r;
                const float* mlp = &ml_lds[rloc * 10];
                float2 a0 = *(const float2*)(mlp + 0);
                float2 a1 = *(const float2*)(mlp + 2);
                float2 a2 = *(const float2*)(mlp + 4);
                float2 a3 = *(const float2*)(mlp + 6);
                float Mt   = fmaxf(fmaxf(a0.x, a1.x), fmaxf(a2.x, a3.x));
                float mnew = fmaxf(m_run[r], Mt);
                float alpha = __expf(m_run[r] - mnew);
                float Ladd = a0.y * __expf(a0.x - mnew) + a1.y * __expf(a1.x - mnew)
                           + a2.y * __expf(a2.x - mnew) + a3.y * __expf(a3.x - mnew);
                l_run[r] = l_run[r] * alpha + Ladd;
                m_run[r] = mnew;
                acc[r] *= alpha;
            }

            // p = exp(s - m_new), dropout, store P as fp16
#pragma unroll
            for (int r = 0; r < 4; ++r) {
                int rw = r0 + rh * 16 + 4 * lg + r;
                float p = __expf(sv[r] - m_run[r]);
                unsigned f = (fb0 | ((unsigned)rw << 11)) + (unsigned)kg;
                float uu = tf_uniform(seed, f);
                float pd = (uu < 0.9f) ? p * (1.0f / 0.9f) : 0.0f;
                P_lds[(rh * 16 + 4 * lg + r) * 72 + (16 * nq + ll)] = (_Float16)pd;
            }
            __syncthreads();   // P ready

            // PV: out-tile rows rh*16+, d-quarter nq; accumulate over 64 keys
#pragma unroll
            for (int ks = 0; ks < 2; ++ks) {
                f16x8 ap = *(const f16x8*)&P_lds[(rh * 16 + ll) * 72 + 8 * lg + 32 * ks];
                int vbase = (16 * ks + 4 * lg) * 68 + 16 * nq + ll;
                u32x4 bw;
                bw.x = V_lds[vbase];
                bw.y = V_lds[vbase + 68];
                bw.z = V_lds[vbase + 136];
                bw.w = V_lds[vbase + 204];
                f16x8 bv = __builtin_bit_cast(f16x8, bw);
                acc = __builtin_amdgcn_mfma_f32_16x16x32_f16(ap, bv, acc, 0, 0, 0);
            }
        }

        // epilogue: normalize; row 0 = dropout(1) * vv[0]
#pragma unroll
        for (int r = 0; r < 4; ++r) {
            int rw = r0 + rh * 16 + 4 * lg + r;
            int dg = 16 * nq + ll;
            float o;
            if (rw == 0) {
                float uu = tf_uniform(seed, fb0);
                o = ((uu < 0.9f) ? (1.0f / 0.9f) : 0.0f) * vh[dg];
            } else {
                o = acc[r] / l_run[r];
            }
            out[headoff + (size_t)rw * DMODEL + dg] = o;
        }
        __syncthreads();   // safe to restage for second tile
    }
}

// ---------------- launcher ----------------
extern "C" void kernel_launch(void* const* d_in, const int* in_sizes, int n_in,
                              void* d_out, int out_size, void* d_ws, size_t ws_size,
                              hipStream_t stream) {
    const float* qk    = (const float*)d_in[0];
    const float* v     = (const float*)d_in[1];
    const float* W_qk  = (const float*)d_in[2];
    const float* W_v   = (const float*)d_in[3];
    const float* W_out = (const float*)d_in[4];
    const float* b_out = (const float*)d_in[5];
    const int*   seedp = (const int*)d_in[6];
    float* out = (float*)d_out;

    const size_t NELT = (size_t)BATCH * SEQ * DMODEL;  // 2,097,152
    float* q_buf  = (float*)d_ws;
    float* vv_buf = q_buf + NELT;
    float* ao_buf = vv_buf + NELT;
    float* qn_buf = ao_buf + NELT;

    const int M = BATCH * SEQ;

    dim3 gb(256);
    dim3 gg(DMODEL / 64, M / 64);
    hipLaunchKernelGGL(gemm64, gg, gb, 0, stream, qk, W_qk, nullptr, q_buf, M, DMODEL, DMODEL);
    hipLaunchKernelGGL(gemm64, gg, gb, 0, stream, v, W_v, nullptr, vv_buf, M, DMODEL, DMODEL);

    hipLaunchKernelGGL(qnorm_kernel, dim3(BATCH * SEQ * NHEAD / 4), dim3(256), 0, stream,
                       q_buf, qn_buf);

    hipLaunchKernelGGL(attn_mfma, dim3(512), dim3(512), 0, stream,
                       q_buf, qn_buf, vv_buf, seedp, ao_buf);

    hipLaunchKernelGGL(gemm64, gg, gb, 0, stream, ao_buf, W_out, b_out, out, M, DMODEL, DMODEL);
}